// Round 1
// baseline (232.838 us; speedup 1.0000x reference)
//
#include <hip/hip_runtime.h>

typedef __attribute__((ext_vector_type(8))) short short8;
typedef __attribute__((ext_vector_type(4))) float f32x4;

#define BB 2
#define TT 2048
#define HH 16
#define DD 64
#define CC 1024

__device__ __forceinline__ unsigned short f2bf(float f) {
  union { float f; unsigned int u; } v; v.f = f;
  unsigned int r = v.u + 0x7fffu + ((v.u >> 16) & 1u);
  return (unsigned short)(r >> 16);
}
__device__ __forceinline__ float bf2f(unsigned short h) {
  union { unsigned int u; float f; } v; v.u = ((unsigned int)h) << 16; return v.f;
}

__global__ void cvt_f32_bf16(const float* __restrict__ in, unsigned short* __restrict__ out, int n) {
  int i = blockIdx.x * blockDim.x + threadIdx.x;
  int stride = gridDim.x * blockDim.x;
  for (; i < n; i += stride) out[i] = f2bf(in[i]);
}

// C = A @ B^T ; A [M,K] bf16, B [N,K] bf16, C [M,N] bf16 or f32
template<bool BF16OUT>
__global__ __launch_bounds__(256) void gemm_bt(const unsigned short* __restrict__ A,
                                               const unsigned short* __restrict__ B,
                                               void* __restrict__ Cv,
                                               int M, int N, int K) {
  constexpr int BK = 64, LDT = BK + 8;           // +8 bf16 pad: rows land 4 banks apart
  __shared__ unsigned short As[128 * LDT];
  __shared__ unsigned short Bs[128 * LDT];
  const int bm = blockIdx.y * 128, bn = blockIdx.x * 128;
  const int tid = threadIdx.x, wave = tid >> 6, lane = tid & 63;
  const int wm = (wave >> 1) * 64, wn = (wave & 1) * 64;
  const int g = lane >> 4, lr = lane & 15;
  f32x4 acc[4][4];
  #pragma unroll
  for (int i = 0; i < 4; ++i)
    #pragma unroll
    for (int j = 0; j < 4; ++j) acc[i][j] = (f32x4){0.f, 0.f, 0.f, 0.f};

  for (int k0 = 0; k0 < K; k0 += BK) {
    __syncthreads();
    #pragma unroll
    for (int p = 0; p < 4; ++p) {
      int r = p * 32 + (tid >> 3);
      int c = (tid & 7) * 8;
      *(short8*)&As[r * LDT + c] = *(const short8*)&A[(size_t)(bm + r) * K + k0 + c];
      *(short8*)&Bs[r * LDT + c] = *(const short8*)&B[(size_t)(bn + r) * K + k0 + c];
    }
    __syncthreads();
    #pragma unroll
    for (int kk = 0; kk < BK; kk += 32) {
      const int kb = kk + g * 8;
      short8 af[4], bf[4];
      #pragma unroll
      for (int i = 0; i < 4; ++i) {
        af[i] = *(const short8*)&As[(wm + i * 16 + lr) * LDT + kb];
        bf[i] = *(const short8*)&Bs[(wn + i * 16 + lr) * LDT + kb];
      }
      #pragma unroll
      for (int i = 0; i < 4; ++i)
        #pragma unroll
        for (int j = 0; j < 4; ++j)
          acc[i][j] = __builtin_amdgcn_mfma_f32_16x16x32_bf16(af[i], bf[j], acc[i][j], 0, 0, 0);
    }
  }
  // C/D layout (verified m89): col = lane&15, row = (lane>>4)*4 + reg
  #pragma unroll
  for (int i = 0; i < 4; ++i) {
    const int row0 = bm + wm + i * 16 + g * 4;
    #pragma unroll
    for (int j = 0; j < 4; ++j) {
      const int col = bn + wn + j * 16 + lr;
      #pragma unroll
      for (int r = 0; r < 4; ++r) {
        float v = acc[i][j][r];
        if (BF16OUT) ((unsigned short*)Cv)[(size_t)(row0 + r) * N + col] = f2bf(v);
        else         ((float*)Cv)[(size_t)(row0 + r) * N + col] = v;
      }
    }
  }
}

// qkv [B*T, 3*C] bf16 -> rope'd q,k and copied v, each [B,H,T,D] bf16
__global__ void rope_reshape(const unsigned short* __restrict__ qkv,
                             const float* __restrict__ cosb, const float* __restrict__ sinb,
                             unsigned short* __restrict__ qo, unsigned short* __restrict__ ko,
                             unsigned short* __restrict__ vo) {
  int idx = blockIdx.x * blockDim.x + threadIdx.x;   // B*T*H*32 = 2,097,152 threads
  int d = idx & 31;
  int h = (idx >> 5) & 15;
  int t = (idx >> 9) & 2047;
  int b = idx >> 20;
  const unsigned short* row = qkv + (size_t)(b * TT + t) * (3 * CC);
  float c = cosb[t * DD + d], s = sinb[t * DD + d];   // cos[t][d] == cos[t][d+32]
  float q1 = bf2f(row[h * DD + d]),            q2 = bf2f(row[h * DD + d + 32]);
  float k1 = bf2f(row[CC + h * DD + d]),       k2 = bf2f(row[CC + h * DD + d + 32]);
  size_t o = (((size_t)(b * HH + h)) * TT + t) * DD + d;
  qo[o]      = f2bf(q1 * c - q2 * s);
  qo[o + 32] = f2bf(q2 * c + q1 * s);
  ko[o]      = f2bf(k1 * c - k2 * s);
  ko[o + 32] = f2bf(k2 * c + k1 * s);
  vo[o]      = row[2 * CC + h * DD + d];
  vo[o + 32] = row[2 * CC + h * DD + d + 32];
}

// Flash attention, causal. Grid: (T/64, B*H). Block 256 = 4 waves, 16 q-rows/wave.
__global__ __launch_bounds__(256) void attn(const unsigned short* __restrict__ qb,
                                            const unsigned short* __restrict__ kb,
                                            const unsigned short* __restrict__ vb,
                                            unsigned short* __restrict__ aout) {
  constexpr int LDT = DD + 8;
  __shared__ unsigned short Ks[64 * LDT];      // [kv][d]
  __shared__ unsigned short Vt[DD * LDT];      // transposed: [d][kv]
  __shared__ unsigned short Pw[4][16 * LDT];   // per-wave P staging [qrow][kv]
  const int bh = blockIdx.y;
  const int qt = blockIdx.x;
  const int qbase = qt * 64;
  const int tid = threadIdx.x, wave = tid >> 6, lane = tid & 63;
  const int g = lane >> 4, lr = lane & 15;
  const unsigned short* Qb = qb + (size_t)bh * TT * DD;
  const unsigned short* Kb = kb + (size_t)bh * TT * DD;
  const unsigned short* Vb = vb + (size_t)bh * TT * DD;

  // Q fragments (A operand): row = lane&15 within strip, k = kk*32 + (lane>>4)*8 + i
  short8 qf[2];
  #pragma unroll
  for (int kk = 0; kk < 2; ++kk)
    qf[kk] = *(const short8*)&Qb[(size_t)(qbase + wave * 16 + lr) * DD + kk * 32 + g * 8];

  f32x4 acc_o[4];
  #pragma unroll
  for (int j = 0; j < 4; ++j) acc_o[j] = (f32x4){0.f, 0.f, 0.f, 0.f};
  float m_i[4], l_i[4];
  #pragma unroll
  for (int r = 0; r < 4; ++r) { m_i[r] = -1e30f; l_i[r] = 0.f; }

  const int ntiles = qt + 1;
  for (int t = 0; t < ntiles; ++t) {
    __syncthreads();
    {  // stage K tile [64][64] and V transposed [64 d][64 kv]
      int r = tid >> 2, c0 = (tid & 3) * 16;
      short8 ka = *(const short8*)&Kb[(size_t)(t * 64 + r) * DD + c0];
      short8 kb2 = *(const short8*)&Kb[(size_t)(t * 64 + r) * DD + c0 + 8];
      *(short8*)&Ks[r * LDT + c0] = ka;
      *(short8*)&Ks[r * LDT + c0 + 8] = kb2;
      short8 va = *(const short8*)&Vb[(size_t)(t * 64 + r) * DD + c0];
      short8 vb2 = *(const short8*)&Vb[(size_t)(t * 64 + r) * DD + c0 + 8];
      #pragma unroll
      for (int e = 0; e < 8; ++e) {
        Vt[(c0 + e) * LDT + r]     = ((const unsigned short*)&va)[e];
        Vt[(c0 + 8 + e) * LDT + r] = ((const unsigned short*)&vb2)[e];
      }
    }
    __syncthreads();

    // S = Q @ K^T  (per wave: 16 x 64)
    f32x4 s[4];
    #pragma unroll
    for (int j = 0; j < 4; ++j) s[j] = (f32x4){0.f, 0.f, 0.f, 0.f};
    #pragma unroll
    for (int kk = 0; kk < 2; ++kk) {
      const int kb8 = kk * 32 + g * 8;
      #pragma unroll
      for (int j = 0; j < 4; ++j) {
        short8 kf = *(const short8*)&Ks[(j * 16 + lr) * LDT + kb8];
        s[j] = __builtin_amdgcn_mfma_f32_16x16x32_bf16(qf[kk], kf, s[j], 0, 0, 0);
      }
    }
    // scale + causal mask (S row = g*4 + r, col = j*16 + lr)
    const bool diag = (t == qt);
    #pragma unroll
    for (int j = 0; j < 4; ++j)
      #pragma unroll
      for (int r = 0; r < 4; ++r) {
        float v = s[j][r] * 0.125f;
        if (diag) {
          int kv = t * 64 + j * 16 + lr;
          int qr = qbase + wave * 16 + g * 4 + r;
          if (kv > qr) v = -1e30f;
        }
        s[j][r] = v;
      }
    // online softmax: each (g, r) pair owns q-row g*4+r; its 16 cols sit in one 16-lane group
    #pragma unroll
    for (int r = 0; r < 4; ++r) {
      float mx = fmaxf(fmaxf(s[0][r], s[1][r]), fmaxf(s[2][r], s[3][r]));
      #pragma unroll
      for (int off = 1; off < 16; off <<= 1) mx = fmaxf(mx, __shfl_xor(mx, off, 64));
      float mnew = fmaxf(m_i[r], mx);
      float scale = __expf(m_i[r] - mnew);
      m_i[r] = mnew;
      float rs = 0.f;
      #pragma unroll
      for (int j = 0; j < 4; ++j) {
        float p = __expf(s[j][r] - mnew);
        s[j][r] = p;
        rs += p;
      }
      #pragma unroll
      for (int off = 1; off < 16; off <<= 1) rs += __shfl_xor(rs, off, 64);
      l_i[r] = l_i[r] * scale + rs;
      #pragma unroll
      for (int j = 0; j < 4; ++j) acc_o[j][r] *= scale;
    }
    // P -> LDS (bf16), then PV
    #pragma unroll
    for (int j = 0; j < 4; ++j)
      #pragma unroll
      for (int r = 0; r < 4; ++r)
        Pw[wave][(g * 4 + r) * LDT + j * 16 + lr] = f2bf(s[j][r]);
    __syncthreads();
    #pragma unroll
    for (int kk = 0; kk < 2; ++kk) {
      short8 pf = *(const short8*)&Pw[wave][lr * LDT + kk * 32 + g * 8];
      #pragma unroll
      for (int j = 0; j < 4; ++j) {
        short8 vf = *(const short8*)&Vt[(j * 16 + lr) * LDT + kk * 32 + g * 8];
        acc_o[j] = __builtin_amdgcn_mfma_f32_16x16x32_bf16(pf, vf, acc_o[j], 0, 0, 0);
      }
    }
  }

  // write O / l  -> aout [B*T, C] bf16, col = h*64 + d
  const int b = bh >> 4, h = bh & 15;
  #pragma unroll
  for (int r = 0; r < 4; ++r) {
    float inv = 1.0f / l_i[r];
    int qr = qbase + wave * 16 + g * 4 + r;
    size_t rowo = ((size_t)b * TT + qr) * CC + h * DD;
    #pragma unroll
    for (int j = 0; j < 4; ++j)
      aout[rowo + j * 16 + lr] = f2bf(acc_o[j][r] * inv);
  }
}

extern "C" void kernel_launch(void* const* d_in, const int* in_sizes, int n_in,
                              void* d_out, int out_size, void* d_ws, size_t ws_size,
                              hipStream_t stream) {
  const float* x   = (const float*)d_in[0];
  const float* wq  = (const float*)d_in[1];
  const float* wk  = (const float*)d_in[2];
  const float* wv  = (const float*)d_in[3];
  const float* wo  = (const float*)d_in[4];
  const float* cosb = (const float*)d_in[5];
  const float* sinb = (const float*)d_in[6];
  float* out = (float*)d_out;
  char* ws = (char*)d_ws;

  const size_t MB = 1u << 20;
  unsigned short* xb    = (unsigned short*)(ws);              //  8 MB [4096,1024]
  unsigned short* wqkvb = (unsigned short*)(ws + 8 * MB);     //  6 MB [3072,1024]
  unsigned short* wob   = (unsigned short*)(ws + 14 * MB);    //  2 MB [1024,1024]
  unsigned short* sqkv  = (unsigned short*)(ws + 16 * MB);    // 24 MB [4096,3072]
  unsigned short* qb2   = (unsigned short*)(ws + 40 * MB);    //  8 MB [B,H,T,D]
  unsigned short* kb2   = (unsigned short*)(ws + 48 * MB);    //  8 MB
  unsigned short* vb2   = (unsigned short*)(ws + 56 * MB);    //  8 MB
  unsigned short* aoutb = (unsigned short*)(ws + 64 * MB);    //  8 MB [4096,1024]

  cvt_f32_bf16<<<2048, 256, 0, stream>>>(x,  xb, 4194304);
  cvt_f32_bf16<<<1024, 256, 0, stream>>>(wq, wqkvb,            1048576);
  cvt_f32_bf16<<<1024, 256, 0, stream>>>(wk, wqkvb + 1048576,  1048576);
  cvt_f32_bf16<<<1024, 256, 0, stream>>>(wv, wqkvb + 2097152,  1048576);
  cvt_f32_bf16<<<1024, 256, 0, stream>>>(wo, wob,              1048576);

  gemm_bt<true><<<dim3(24, 32), 256, 0, stream>>>(xb, wqkvb, sqkv, 4096, 3072, 1024);
  rope_reshape<<<8192, 256, 0, stream>>>(sqkv, cosb, sinb, qb2, kb2, vb2);
  attn<<<dim3(32, 32), 256, 0, stream>>>(qb2, kb2, vb2, aoutb);
  gemm_bt<false><<<dim3(8, 32), 256, 0, stream>>>(aoutb, wob, out, 4096, 1024, 1024);
}

// Round 2
// 215.399 us; speedup vs baseline: 1.0810x; 1.0810x over previous
//
#include <hip/hip_runtime.h>

typedef __attribute__((ext_vector_type(8))) short short8;
typedef __attribute__((ext_vector_type(4))) float f32x4;

#define BB 2
#define TT 2048
#define HH 16
#define DD 64
#define CC 1024

__device__ __forceinline__ unsigned short f2bf(float f) {
  union { float f; unsigned int u; } v; v.f = f;
  unsigned int r = v.u + 0x7fffu + ((v.u >> 16) & 1u);
  return (unsigned short)(r >> 16);
}
__device__ __forceinline__ float bf2f(unsigned short h) {
  union { unsigned int u; float f; } v; v.u = ((unsigned int)h) << 16; return v.f;
}

__global__ void cvt_f32_bf16(const float* __restrict__ in, unsigned short* __restrict__ out, int n) {
  int i = blockIdx.x * blockDim.x + threadIdx.x;
  int stride = gridDim.x * blockDim.x;
  for (; i < n; i += stride) out[i] = f2bf(in[i]);
}

// C = A @ B^T ; A [M,K] bf16, B [N,K] bf16, C [M,N] bf16 or f32
template<bool BF16OUT>
__global__ __launch_bounds__(256) void gemm_bt(const unsigned short* __restrict__ A,
                                               const unsigned short* __restrict__ B,
                                               void* __restrict__ Cv,
                                               int M, int N, int K) {
  constexpr int BK = 64, LDT = BK + 8;
  __shared__ unsigned short As[128 * LDT];
  __shared__ unsigned short Bs[128 * LDT];
  const int bm = blockIdx.y * 128, bn = blockIdx.x * 128;
  const int tid = threadIdx.x, wave = tid >> 6, lane = tid & 63;
  const int wm = (wave >> 1) * 64, wn = (wave & 1) * 64;
  const int g = lane >> 4, lr = lane & 15;
  f32x4 acc[4][4];
  #pragma unroll
  for (int i = 0; i < 4; ++i)
    #pragma unroll
    for (int j = 0; j < 4; ++j) acc[i][j] = (f32x4){0.f, 0.f, 0.f, 0.f};

  for (int k0 = 0; k0 < K; k0 += BK) {
    __syncthreads();
    #pragma unroll
    for (int p = 0; p < 4; ++p) {
      int r = p * 32 + (tid >> 3);
      int c = (tid & 7) * 8;
      *(short8*)&As[r * LDT + c] = *(const short8*)&A[(size_t)(bm + r) * K + k0 + c];
      *(short8*)&Bs[r * LDT + c] = *(const short8*)&B[(size_t)(bn + r) * K + k0 + c];
    }
    __syncthreads();
    #pragma unroll
    for (int kk = 0; kk < BK; kk += 32) {
      const int kb = kk + g * 8;
      short8 af[4], bf[4];
      #pragma unroll
      for (int i = 0; i < 4; ++i) {
        af[i] = *(const short8*)&As[(wm + i * 16 + lr) * LDT + kb];
        bf[i] = *(const short8*)&Bs[(wn + i * 16 + lr) * LDT + kb];
      }
      #pragma unroll
      for (int i = 0; i < 4; ++i)
        #pragma unroll
        for (int j = 0; j < 4; ++j)
          acc[i][j] = __builtin_amdgcn_mfma_f32_16x16x32_bf16(af[i], bf[j], acc[i][j], 0, 0, 0);
    }
  }
  #pragma unroll
  for (int i = 0; i < 4; ++i) {
    const int row0 = bm + wm + i * 16 + g * 4;
    #pragma unroll
    for (int j = 0; j < 4; ++j) {
      const int col = bn + wn + j * 16 + lr;
      #pragma unroll
      for (int r = 0; r < 4; ++r) {
        float v = acc[i][j][r];
        if (BF16OUT) ((unsigned short*)Cv)[(size_t)(row0 + r) * N + col] = f2bf(v);
        else         ((float*)Cv)[(size_t)(row0 + r) * N + col] = v;
      }
    }
  }
}

// qkv [B*T, 3*C] bf16 -> rope'd q (pre-scaled by 1/8) and k, each [B,H,T,D] bf16
__global__ void rope_qk(const unsigned short* __restrict__ qkv,
                        const float* __restrict__ cosb, const float* __restrict__ sinb,
                        unsigned short* __restrict__ qo, unsigned short* __restrict__ ko) {
  int idx = blockIdx.x * blockDim.x + threadIdx.x;   // B*T*H*32 = 2,097,152 threads
  int d = idx & 31;
  int h = (idx >> 5) & 15;
  int t = (idx >> 9) & 2047;
  int b = idx >> 20;
  const unsigned short* row = qkv + (size_t)(b * TT + t) * (3 * CC);
  float c = cosb[t * DD + d], s = sinb[t * DD + d];   // cos[t][d] == cos[t][d+32]
  float q1 = bf2f(row[h * DD + d]),      q2 = bf2f(row[h * DD + d + 32]);
  float k1 = bf2f(row[CC + h * DD + d]), k2 = bf2f(row[CC + h * DD + d + 32]);
  size_t o = (((size_t)(b * HH + h)) * TT + t) * DD + d;
  qo[o]      = f2bf(0.125f * (q1 * c - q2 * s));   // fold softmax scale 1/sqrt(64) into q
  qo[o + 32] = f2bf(0.125f * (q2 * c + q1 * s));
  ko[o]      = f2bf(k1 * c - k2 * s);
  ko[o + 32] = f2bf(k2 * c + k1 * s);
}

// V slice of qkv -> vt [B,H,D,T] (transposed), LDS tiled, coalesced both sides
__global__ __launch_bounds__(256) void vtrans(const unsigned short* __restrict__ qkv,
                                              unsigned short* __restrict__ vt) {
  __shared__ unsigned short tile[64 * 72];
  const int bh = blockIdx.y, b = bh >> 4, h = bh & 15;
  const int t0 = blockIdx.x * 64;
  const int tid = threadIdx.x;
  const int r = tid >> 2, c0 = (tid & 3) * 16;
  const unsigned short* src = qkv + (size_t)(b * TT + t0 + r) * (3 * CC) + 2 * CC + h * DD + c0;
  *(short8*)&tile[r * 72 + c0]     = *(const short8*)src;
  *(short8*)&tile[r * 72 + c0 + 8] = *(const short8*)(src + 8);
  __syncthreads();
  short8 o0, o1;
  #pragma unroll
  for (int e = 0; e < 8; ++e) {
    ((unsigned short*)&o0)[e] = tile[(c0 + e) * 72 + r];
    ((unsigned short*)&o1)[e] = tile[(c0 + 8 + e) * 72 + r];
  }
  size_t dst = ((size_t)(bh * DD + r)) * TT + t0 + c0;
  *(short8*)&vt[dst]     = o0;
  *(short8*)&vt[dst + 8] = o1;
}

// Flash attention, causal. Grid: (T/128, B*H). Block 256 = 4 waves, 32 q-rows/wave (2 strips).
__global__ __launch_bounds__(256) void attn2(const unsigned short* __restrict__ qb,
                                             const unsigned short* __restrict__ kb,
                                             const unsigned short* __restrict__ vt,
                                             unsigned short* __restrict__ aout) {
  constexpr int LDT = 72;
  __shared__ unsigned short Ks[64 * LDT];      // [kv][d]
  __shared__ unsigned short Vs[64 * LDT];      // [d][kv]  (from pre-transposed vt)
  __shared__ unsigned short Pw[4][16 * LDT];   // per-wave P staging [qrow][kv]
  const int bh = blockIdx.y;
  const int qi = (int)gridDim.x - 1 - (int)blockIdx.x;  // heavy blocks first
  const int qbase = qi * 128;
  const int tid = threadIdx.x, wave = tid >> 6, lane = tid & 63;
  const int g = lane >> 4, lr = lane & 15;
  const unsigned short* Qb  = qb + (size_t)bh * TT * DD;
  const unsigned short* Kb  = kb + (size_t)bh * TT * DD;
  const unsigned short* Vtb = vt + (size_t)bh * DD * TT;

  short8 qf[2][2];
  #pragma unroll
  for (int s = 0; s < 2; ++s)
    #pragma unroll
    for (int kk = 0; kk < 2; ++kk)
      qf[s][kk] = *(const short8*)&Qb[(size_t)(qbase + wave * 32 + s * 16 + lr) * DD + kk * 32 + g * 8];

  f32x4 acc[2][4];
  float m_i[2][4], l_i[2][4];
  #pragma unroll
  for (int s = 0; s < 2; ++s)
    #pragma unroll
    for (int j = 0; j < 4; ++j) {
      acc[s][j] = (f32x4){0.f, 0.f, 0.f, 0.f};
      m_i[s][j] = -1e30f; l_i[s][j] = 0.f;
    }

  const int sr = tid >> 2, sc = (tid & 3) * 16;
  const int ntiles = 2 * qi + 2;
  for (int t = 0; t < ntiles; ++t) {
    __syncthreads();
    {
      const unsigned short* ksrc = Kb + (size_t)(t * 64 + sr) * DD + sc;
      *(short8*)&Ks[sr * LDT + sc]     = *(const short8*)ksrc;
      *(short8*)&Ks[sr * LDT + sc + 8] = *(const short8*)(ksrc + 8);
      const unsigned short* vsrc = Vtb + (size_t)sr * TT + t * 64 + sc;
      *(short8*)&Vs[sr * LDT + sc]     = *(const short8*)vsrc;
      *(short8*)&Vs[sr * LDT + sc + 8] = *(const short8*)(vsrc + 8);
    }
    __syncthreads();

    #pragma unroll
    for (int s = 0; s < 2; ++s) {
      const int rowbase = qbase + wave * 32 + s * 16;
      f32x4 sv[4];
      #pragma unroll
      for (int j = 0; j < 4; ++j) sv[j] = (f32x4){0.f, 0.f, 0.f, 0.f};
      #pragma unroll
      for (int kk = 0; kk < 2; ++kk) {
        const int kb8 = kk * 32 + g * 8;
        #pragma unroll
        for (int j = 0; j < 4; ++j) {
          short8 kf = *(const short8*)&Ks[(j * 16 + lr) * LDT + kb8];
          sv[j] = __builtin_amdgcn_mfma_f32_16x16x32_bf16(qf[s][kk], kf, sv[j], 0, 0, 0);
        }
      }
      if (t * 64 + 63 > rowbase) {   // only diagonal tiles pay mask VALU
        #pragma unroll
        for (int j = 0; j < 4; ++j)
          #pragma unroll
          for (int r = 0; r < 4; ++r) {
            int kv = t * 64 + j * 16 + lr;
            int qr = rowbase + g * 4 + r;
            if (kv > qr) sv[j][r] = -1e30f;
          }
      }
      #pragma unroll
      for (int r = 0; r < 4; ++r) {
        float mx = fmaxf(fmaxf(sv[0][r], sv[1][r]), fmaxf(sv[2][r], sv[3][r]));
        #pragma unroll
        for (int off = 1; off < 16; off <<= 1) mx = fmaxf(mx, __shfl_xor(mx, off, 64));
        float mnew = fmaxf(m_i[s][r], mx);
        float scl = __expf(m_i[s][r] - mnew);
        m_i[s][r] = mnew;
        float rs = 0.f;
        #pragma unroll
        for (int j = 0; j < 4; ++j) {
          float p = __expf(sv[j][r] - mnew);
          sv[j][r] = p;
          rs += p;
        }
        #pragma unroll
        for (int off = 1; off < 16; off <<= 1) rs += __shfl_xor(rs, off, 64);
        l_i[s][r] = l_i[s][r] * scl + rs;
        #pragma unroll
        for (int j = 0; j < 4; ++j) acc[s][j][r] *= scl;
      }
      // P staging is wave-private: no block barrier needed (in-wave ds ordering)
      #pragma unroll
      for (int j = 0; j < 4; ++j)
        #pragma unroll
        for (int r = 0; r < 4; ++r)
          Pw[wave][(g * 4 + r) * LDT + j * 16 + lr] = f2bf(sv[j][r]);
      #pragma unroll
      for (int kk = 0; kk < 2; ++kk) {
        short8 pf = *(const short8*)&Pw[wave][lr * LDT + kk * 32 + g * 8];
        #pragma unroll
        for (int j = 0; j < 4; ++j) {
          short8 vf = *(const short8*)&Vs[(j * 16 + lr) * LDT + kk * 32 + g * 8];
          acc[s][j] = __builtin_amdgcn_mfma_f32_16x16x32_bf16(pf, vf, acc[s][j], 0, 0, 0);
        }
      }
    }
  }

  const int b = bh >> 4, h = bh & 15;
  #pragma unroll
  for (int s = 0; s < 2; ++s)
    #pragma unroll
    for (int r = 0; r < 4; ++r) {
      float inv = 1.0f / l_i[s][r];
      int qr = qbase + wave * 32 + s * 16 + g * 4 + r;
      size_t rowo = ((size_t)b * TT + qr) * CC + h * DD;
      #pragma unroll
      for (int j = 0; j < 4; ++j)
        aout[rowo + j * 16 + lr] = f2bf(acc[s][j][r] * inv);
    }
}

extern "C" void kernel_launch(void* const* d_in, const int* in_sizes, int n_in,
                              void* d_out, int out_size, void* d_ws, size_t ws_size,
                              hipStream_t stream) {
  const float* x    = (const float*)d_in[0];
  const float* wq   = (const float*)d_in[1];
  const float* wk   = (const float*)d_in[2];
  const float* wv   = (const float*)d_in[3];
  const float* wo   = (const float*)d_in[4];
  const float* cosb = (const float*)d_in[5];
  const float* sinb = (const float*)d_in[6];
  float* out = (float*)d_out;
  char* ws = (char*)d_ws;

  const size_t MB = 1u << 20;
  unsigned short* xb    = (unsigned short*)(ws);              //  8 MB [4096,1024]
  unsigned short* wqkvb = (unsigned short*)(ws + 8 * MB);     //  6 MB [3072,1024]
  unsigned short* wob   = (unsigned short*)(ws + 14 * MB);    //  2 MB [1024,1024]
  unsigned short* sqkv  = (unsigned short*)(ws + 16 * MB);    // 24 MB [4096,3072]
  unsigned short* qb2   = (unsigned short*)(ws + 40 * MB);    //  8 MB [B,H,T,D]
  unsigned short* kb2   = (unsigned short*)(ws + 48 * MB);    //  8 MB [B,H,T,D]
  unsigned short* vtb   = (unsigned short*)(ws + 56 * MB);    //  8 MB [B,H,D,T]
  unsigned short* aoutb = (unsigned short*)(ws + 64 * MB);    //  8 MB [4096,1024]

  cvt_f32_bf16<<<2048, 256, 0, stream>>>(x,  xb, 4194304);
  cvt_f32_bf16<<<1024, 256, 0, stream>>>(wq, wqkvb,           1048576);
  cvt_f32_bf16<<<1024, 256, 0, stream>>>(wk, wqkvb + 1048576, 1048576);
  cvt_f32_bf16<<<1024, 256, 0, stream>>>(wv, wqkvb + 2097152, 1048576);
  cvt_f32_bf16<<<1024, 256, 0, stream>>>(wo, wob,             1048576);

  gemm_bt<true><<<dim3(24, 32), 256, 0, stream>>>(xb, wqkvb, sqkv, 4096, 3072, 1024);
  rope_qk<<<8192, 256, 0, stream>>>(sqkv, cosb, sinb, qb2, kb2);
  vtrans<<<dim3(32, 32), 256, 0, stream>>>(sqkv, vtb);
  attn2<<<dim3(16, 32), 256, 0, stream>>>(qb2, kb2, vtb, aoutb);
  gemm_bt<false><<<dim3(8, 32), 256, 0, stream>>>(aoutb, wob, out, 4096, 1024, 1024);
}